// Round 2
// baseline (872.518 us; speedup 1.0000x reference)
//
#include <hip/hip_runtime.h>

// R9: overlapped software pipeline. R8 (575us) was phase-serialized:
// [P0-MFMA][act0][bar][P1-MFMA][act1] -> MFMA pipe idle during act and
// vice versa (MfmaUtil 35 + VALUBusy 51, wall ~4850cy/step vs ~1940 MFMA
// + ~1500 act). Rotate the pipeline so each act overlaps MFMAs writing
// the OTHER accumulator:
//   A: acc0 = Wx*x(s) + WH0*h0(s-1)   (20 MFMA)  || act1(s-1) [acc1]
//   B: acc1 = b1 + WH1*h1(s-1)        (16 MFMA)  || act0(s)   [acc0]
//   B1 barrier
//   C: acc1 += WI1*h0(s)              (16 MFMA, exposed: reads act0 output)
// acc0+acc1 live together = +16 VGPRs; budget was exactly full (R5b: +16
// spills). Paid for by demoting WI1 kt=3 slice (16 regs) to per-step L2
// loads: asm volatile global_load_dwordx4 (volatile = not LICM-hoistable
// back into persistent regs), consumed last after vmcnt(0)+sched_barrier
// (guide rule #18). Spill tripwire: WRITE_SIZE must stay 1920KB.
// sh1 is now single-buffered (store -> barrier -> read same step is safe).

typedef _Float16 half_t;
typedef _Float16 half8 __attribute__((ext_vector_type(8)));
typedef _Float16 half4 __attribute__((ext_vector_type(4)));
typedef float f32x4 __attribute__((ext_vector_type(4)));

#define SEQ 100
#define FUT 30
#define TOT (SEQ + FUT)
#define NIN 15
#define MB  16
#define L2E 1.44269504f
#define SH  136   // h-tile row stride in halfs (272B = 17*16B: aligned, bank-spread)
#define SXS 20    // x-tile row stride in halfs (40B: bank-spread, 8B-aligned)

#define MFMA32(A, B, C) __builtin_amdgcn_mfma_f32_16x16x32_f16((A), (B), (C), 0, 0, 0)
#define MFMA16(A, B, C) __builtin_amdgcn_mfma_f32_16x16x16f16((A), (B), (C), 0, 0, 0)

// ---- prep: fp16 repack, gate scales folded (i,f,o: -log2e ; cell g: +2log2e).
// n' = 64*wave + 16*gate + unit%16, unit j = 16*wave + (n&15), row = g*128 + j.
// ws halfword layout:
//   [0,      65536)  WH0[n*128+k]
//   [65536, 131072)  WI1[n*128+k]
//   [131072,196608)  WH1[n*128+k]
//   [196608,204800)  WX [n*16+k]   (k<15: w_ih0 ; k==15: scaled layer-0 bias)
//   [204800,206848)  BV: 1024 f32 = scaled (b_ih+b_hh), layer0 then layer1
__global__ void prep_kernel(const float* __restrict__ w_ih0, const float* __restrict__ w_hh0,
                            const float* __restrict__ b_ih0, const float* __restrict__ b_hh0,
                            const float* __restrict__ w_ih1, const float* __restrict__ w_hh1,
                            const float* __restrict__ b_ih1, const float* __restrict__ b_hh1,
                            half_t* __restrict__ wsh)
{
  int idx = blockIdx.x * 256 + threadIdx.x;
  if (idx < 196608) {
    int seg = idx >> 16;
    int r   = idx & 65535;
    int n   = r >> 7, k = r & 127;
    int g   = (n >> 4) & 3;
    int row = g * 128 + ((n >> 6) << 4) + (n & 15);
    float sc = (g == 2) ? (2.0f * L2E) : (-L2E);
    const float* src = (seg == 0) ? w_hh0 : ((seg == 1) ? w_ih1 : w_hh1);
    wsh[idx] = (half_t)(src[row * 128 + k] * sc);
  } else if (idx < 204800) {
    int r   = idx - 196608;
    int n   = r >> 4, k = r & 15;
    int g   = (n >> 4) & 3;
    int row = g * 128 + ((n >> 6) << 4) + (n & 15);
    float sc = (g == 2) ? (2.0f * L2E) : (-L2E);
    float v;
    if (k < NIN) v = w_ih0[row * NIN + k] * sc;
    else         v = (b_ih0[row] + b_hh0[row]) * sc;   // bias rides x[15]==1.0
    wsh[idx] = (half_t)v;
  } else if (idx < 205824) {
    int r     = idx - 204800;
    float* bv = (float*)(wsh + 204800);
    int which = r >> 9, n = r & 511;
    int g     = (n >> 4) & 3;
    int row   = g * 128 + ((n >> 6) << 4) + (n & 15);
    float sc  = (g == 2) ? (2.0f * L2E) : (-L2E);
    bv[r] = ((which == 0) ? (b_ih0[row] + b_hh0[row]) : (b_ih1[row] + b_hh1[row])) * sc;
  }
}

__global__ __launch_bounds__(512, 2)
void lstm_kernel(const float* __restrict__ x,
                 const half_t* __restrict__ wsh,
                 const float* __restrict__ fcw,
                 const float* __restrict__ fcb,
                 float* __restrict__ out)
{
  __shared__ __align__(16) half_t sx[SEQ * MB * SXS];   // 64,000 B
  __shared__ __align__(16) half_t sh0[2][MB * SH];      // 8,704 B
  __shared__ __align__(16) half_t sh1[MB * SH];         // 4,352 B (single buffer)
  __shared__ __align__(16) half_t swx[512 * SXS];       // 20,480 B
  __shared__ __align__(16) half_t sdec[MB * SXS];       // 640 B
  __shared__ __align__(16) float  sbias[512];           // layer-1 bias
  __shared__ __align__(16) float  sfc[258];

  const half_t* WH0 = wsh;
  const half_t* WI1 = wsh + 65536;
  const half_t* WH1 = wsh + 131072;
  const half_t* WX  = wsh + 196608;
  const float*  BV  = (const float*)(wsh + 204800);

  const int tid   = threadIdx.x;
  const int wave  = tid >> 6;
  const int lane  = tid & 63;
  const int l16   = lane & 15;
  const int quad  = lane >> 4;
  const int nb    = wave * 64;
  const int bbase = blockIdx.x * MB;
  const int wcol  = wave * 16 + l16;   // h-store column for this lane

  // ---- persistent B-fragments: wh0 full (64), wh1 full (64), wi1 kt=0..2 (48) ----
  half8 wh0[4][4], wh1[4][4], wi1[3][4];
  #pragma unroll
  for (int kt = 0; kt < 4; ++kt) {
    #pragma unroll
    for (int g = 0; g < 4; ++g) {
      int n = nb + g * 16 + l16;
      int k = kt * 32 + quad * 8;
      wh0[kt][g] = *(const half8*)&WH0[n * 128 + k];
      wh1[kt][g] = *(const half8*)&WH1[n * 128 + k];
      if (kt < 3) wi1[kt][g] = *(const half8*)&WI1[n * 128 + k];
    }
  }

  // ---- one-time LDS staging ----
  for (int it = tid; it < MB * SEQ * NIN; it += 512) {
    int b = it / (SEQ * NIN); int r = it - b * (SEQ * NIN);
    int s = r / NIN;          int i = r - s * NIN;
    sx[(s * MB + b) * SXS + i] = (half_t)x[(size_t)(bbase + b) * (SEQ * NIN) + r];
  }
  for (int it = tid; it < SEQ * MB; it += 512) sx[it * SXS + 15] = (half_t)1.0f;  // bias carrier
  for (int it = tid; it < 8192; it += 512) {
    int n = it >> 4, k = it & 15;
    swx[n * SXS + k] = WX[it];
  }
  for (int it = tid; it < 512; it += 512) sbias[it] = BV[512 + it];
  if (tid < 256) sfc[tid] = fcw[tid];
  if (tid < 2)   sfc[256 + tid] = fcb[tid];
  if (tid < 256) {
    int b = tid >> 4, i = tid & 15;
    sdec[b * SXS + i] = (i < NIN) ? (half_t)x[(size_t)(bbase + b) * (SEQ * NIN) + 99 * NIN + i]
                                  : (half_t)1.0f;   // bias carrier
  }
  for (int it = tid; it < MB * SH; it += 512) {
    sh0[0][it] = (half_t)0; sh0[1][it] = (half_t)0; sh1[it] = (half_t)0;
  }
  __syncthreads();

  float c0[4] = {0.f, 0.f, 0.f, 0.f};
  float c1[4] = {0.f, 0.f, 0.f, 0.f};
  f32x4 acc0[4], acc1[4];

  // fused activation (R6-verified): 5 exp2 + 2 rcp per element.
  #define ACT_STORE(ACC, CS, DST)                                              \
    _Pragma("unroll")                                                          \
    for (int r = 0; r < 4; ++r) {                                              \
      float A  = __builtin_amdgcn_exp2f((ACC)[0][r]);                          \
      float C  = __builtin_amdgcn_exp2f((ACC)[1][r]);                          \
      float B  = __builtin_amdgcn_exp2f((ACC)[2][r]);                          \
      float D  = __builtin_amdgcn_exp2f((ACC)[3][r]);                          \
      float oA = 1.f + A, oB = 1.f + B, oC = 1.f + C, oD = 1.f + D;            \
      float P  = oA * oB;                                                      \
      float t  = (B - 1.f) * oC;                                               \
      float nm = fmaf((CS)[r], P, t);                                          \
      float rc = __builtin_amdgcn_rcpf(P * oC);                                \
      float cn = nm * rc;                                                      \
      (CS)[r] = cn;                                                            \
      float E  = __builtin_amdgcn_exp2f(2.0f * L2E * cn);                      \
      float h  = (E - 1.f) * __builtin_amdgcn_rcpf(oD * (1.f + E));            \
      int   m  = quad * 4 + r;                                                 \
      (DST)[m * SH + wcol] = (half_t)h;                                        \
    }

  int cur = 0;
  for (int s = 0; s <= TOT; ++s) {
    const int nxt = cur ^ 1;

    // ========== Phase A: acc0 h-part (+enc x-part)  ||  act1(s-1) ==========
    if (s < TOT) {
      #pragma unroll
      for (int g = 0; g < 4; ++g) acc0[g] = (f32x4){0.f, 0.f, 0.f, 0.f};
      #pragma unroll
      for (int kt = 0; kt < 4; ++kt) {
        int c = kt * 4 + quad;
        half8 ah = *(const half8*)&sh0[cur][l16 * SH + c * 8];
        #pragma unroll
        for (int g = 0; g < 4; ++g) acc0[g] = MFMA32(ah, wh0[kt][g], acc0[g]);
      }
      if (s < SEQ) {  // encoder x-part early (adds to the ||act1 MFMA pool)
        half4 ax = *(const half4*)&sx[s * MB * SXS + l16 * SXS + quad * 4];
        #pragma unroll
        for (int g = 0; g < 4; ++g) {
          half4 bx = *(const half4*)&swx[(nb + g * 16 + l16) * SXS + quad * 4];
          acc0[g] = MFMA16(ax, bx, acc0[g]);
        }
      }
    }
    if (s > 0) { ACT_STORE(acc1, c1, sh1) }   // h1(s-1) -> sh1

    // ---- decoder FC(t = s-1) ----
    if (s > SEQ) {
      __syncthreads();  // B2d: h1(s-1) visible
      if (tid < 256) {
        int b   = wave * 4 + (lane >> 4);
        int o   = (lane >> 3) & 1;
        int seg = lane & 7;
        float p = 0.f;
        #pragma unroll
        for (int cc = 0; cc < 2; ++cc) {
          int c = seg * 2 + cc;
          half8 hv = *(const half8*)&sh1[b * SH + c * 8];
          f32x4 w0 = *(const f32x4*)&sfc[o * 128 + c * 8];
          f32x4 w1 = *(const f32x4*)&sfc[o * 128 + c * 8 + 4];
          #pragma unroll
          for (int u = 0; u < 4; ++u) p = fmaf((float)hv[u], w0[u], p);
          #pragma unroll
          for (int u = 0; u < 4; ++u) p = fmaf((float)hv[4 + u], w1[u], p);
        }
        p += __shfl_down(p, 4);
        p += __shfl_down(p, 2);
        p += __shfl_down(p, 1);
        if (seg == 0) {
          p += sfc[256 + o];
          out[(size_t)(bbase + b) * (FUT * 2) + (s - 1 - SEQ) * 2 + o] = p;
          sdec[b * SXS + o] = (half_t)p;   // feedback into features 0:2
        }
      }
      __syncthreads();  // B3d: sdec visible (also serves as the A->B barrier)
    }
    if (s == TOT) break;   // epilogue: final act1+FC done above

    if (s >= SEQ) {  // decoder x-part late (after sdec feedback)
      half4 ax = *(const half4*)&sdec[l16 * SXS + quad * 4];
      #pragma unroll
      for (int g = 0; g < 4; ++g) {
        half4 bx = *(const half4*)&swx[(nb + g * 16 + l16) * SXS + quad * 4];
        acc0[g] = MFMA16(ax, bx, acc0[g]);
      }
    }
    if (s <= SEQ) __syncthreads();  // B2: h1(s-1) stores -> WH1 reads (enc path)

    // ========== Phase B: acc1 = b1 + WH1*h1(s-1)  ||  act0(s) ==========
    #pragma unroll
    for (int g = 0; g < 4; ++g) {
      float b = sbias[nb + g * 16 + l16];
      acc1[g] = (f32x4){b, b, b, b};
    }
    #pragma unroll
    for (int kt = 0; kt < 4; ++kt) {
      int c = kt * 4 + quad;
      half8 ah = *(const half8*)&sh1[l16 * SH + c * 8];
      #pragma unroll
      for (int g = 0; g < 4; ++g) acc1[g] = MFMA32(ah, wh1[kt][g], acc1[g]);
    }
    ACT_STORE(acc0, c0, (&sh0[nxt][0]))   // h0(s) -> sh0[nxt]
    __syncthreads();  // B1: h0(s) visible

    // ========== Phase C: acc1 += WI1*h0(s) (exposed) ==========
    {
      half8 w3[4];
      #pragma unroll
      for (int g = 0; g < 4; ++g) {
        const half_t* p = &WI1[(size_t)(nb + g * 16 + l16) * 128 + 96 + quad * 8];
        asm volatile("global_load_dwordx4 %0, %1, off" : "=v"(w3[g]) : "v"(p));
      }
      #pragma unroll
      for (int kt = 0; kt < 3; ++kt) {
        int c = kt * 4 + quad;
        half8 ah = *(const half8*)&sh0[nxt][l16 * SH + c * 8];
        #pragma unroll
        for (int g = 0; g < 4; ++g) acc1[g] = MFMA32(ah, wi1[kt][g], acc1[g]);
      }
      {
        int c = 12 + quad;
        half8 ah = *(const half8*)&sh0[nxt][l16 * SH + c * 8];
        asm volatile("s_waitcnt vmcnt(0)");
        __builtin_amdgcn_sched_barrier(0);   // rule #18: don't hoist MFMA above the wait
        #pragma unroll
        for (int g = 0; g < 4; ++g) acc1[g] = MFMA32(ah, w3[g], acc1[g]);
      }
    }

    cur = nxt;
  }
}

extern "C" void kernel_launch(void* const* d_in, const int* in_sizes, int n_in,
                              void* d_out, int out_size, void* d_ws, size_t ws_size,
                              hipStream_t stream)
{
  (void)in_sizes; (void)n_in; (void)out_size; (void)ws_size;
  const float* x     = (const float*)d_in[0];
  const float* w_ih0 = (const float*)d_in[1];
  const float* w_hh0 = (const float*)d_in[2];
  const float* b_ih0 = (const float*)d_in[3];
  const float* b_hh0 = (const float*)d_in[4];
  const float* w_ih1 = (const float*)d_in[5];
  const float* w_hh1 = (const float*)d_in[6];
  const float* b_ih1 = (const float*)d_in[7];
  const float* b_hh1 = (const float*)d_in[8];
  const float* fcw   = (const float*)d_in[9];
  const float* fcb   = (const float*)d_in[10];
  float*  out = (float*)d_out;
  half_t* wsh = (half_t*)d_ws;

  prep_kernel<<<(205824 + 255) / 256, 256, 0, stream>>>(
      w_ih0, w_hh0, b_ih0, b_hh0, w_ih1, w_hh1, b_ih1, b_hh1, wsh);
  lstm_kernel<<<8192 / MB, 512, 0, stream>>>(x, wsh, fcw, fcb, out);
}

// Round 4
// 676.396 us; speedup vs baseline: 1.2900x; 1.2900x over previous
//
#include <hip/hip_runtime.h>

// R11 = R10 resubmit (infra failure, no counters) with defensive LDS trim:
// R10's 158.6KB was within 3% of the 160KiB hw limit - if the runtime
// reserves any workgroup LDS, dispatch fails at container level. sx/sdec
// drop padding (stride 20->16 halfs): LDS 158.6 -> 145.7KB. Only cost is
// a ~4-way conflict on the single per-step ax ds_read_b64 (noise).
// Design (from R9/R10): rotated pipeline so acts overlap MFMAs of the
// OTHER accumulator:
//   A: acc0 = WH0*h0(s-1) (+x MFMA)      || act1(s-1) -> sh1
//   B: acc1 = b1 + WH1*h1(s-1)           || act0(s)   -> sh0[nxt]
//   B1 barrier
//   C: acc1 += WI1*h0(s)  (kt 0..2 persistent regs, kt 3 from LDS swi1h)
// Register economics: wi1 kt=3 slice lives in padded LDS (stride 40 halfs,
// 16B-aligned rows) read per step via laundered 32-bit index (asm "+v"
// blocks LICM re-hoisting); c0/c1 cell state demoted to LDS f32x4 slots
// (conflict-free 16B lane stride), prefetched at phase tops.
// Tripwire: WRITE_SIZE must be 1920KB (output only). Any rise = spill.

typedef _Float16 half_t;
typedef _Float16 half8 __attribute__((ext_vector_type(8)));
typedef _Float16 half4 __attribute__((ext_vector_type(4)));
typedef float f32x4 __attribute__((ext_vector_type(4)));

#define SEQ 100
#define FUT 30
#define TOT (SEQ + FUT)
#define NIN 15
#define MB  16
#define L2E 1.44269504f
#define SH  136   // h-tile row stride in halfs (272B = 17*16B: aligned, bank-spread)
#define SXS 20    // swx row stride in halfs (40B: conflict-free bank walk)
#define SXX 16    // sx/sdec row stride in halfs (32B: compact; ax read ~4-way, 1/step)
#define SW3 40    // swi1h row stride in halfs (80B: 16B-aligned, 2-way banks)

#define MFMA32(A, B, C) __builtin_amdgcn_mfma_f32_16x16x32_f16((A), (B), (C), 0, 0, 0)
#define MFMA16(A, B, C) __builtin_amdgcn_mfma_f32_16x16x16f16((A), (B), (C), 0, 0, 0)

// ---- prep: fp16 repack, gate scales folded (i,f,o: -log2e ; cell g: +2log2e).
// n' = 64*wave + 16*gate + unit%16, unit j = 16*wave + (n&15), row = g*128 + j.
// ws halfword layout:
//   [0,      65536)  WH0[n*128+k]
//   [65536, 131072)  WI1[n*128+k]
//   [131072,196608)  WH1[n*128+k]
//   [196608,204800)  WX [n*16+k]   (k<15: w_ih0 ; k==15: scaled layer-0 bias)
//   [204800,206848)  BV: 1024 f32 = scaled (b_ih+b_hh), layer0 then layer1
__global__ void prep_kernel(const float* __restrict__ w_ih0, const float* __restrict__ w_hh0,
                            const float* __restrict__ b_ih0, const float* __restrict__ b_hh0,
                            const float* __restrict__ w_ih1, const float* __restrict__ w_hh1,
                            const float* __restrict__ b_ih1, const float* __restrict__ b_hh1,
                            half_t* __restrict__ wsh)
{
  int idx = blockIdx.x * 256 + threadIdx.x;
  if (idx < 196608) {
    int seg = idx >> 16;
    int r   = idx & 65535;
    int n   = r >> 7, k = r & 127;
    int g   = (n >> 4) & 3;
    int row = g * 128 + ((n >> 6) << 4) + (n & 15);
    float sc = (g == 2) ? (2.0f * L2E) : (-L2E);
    const float* src = (seg == 0) ? w_hh0 : ((seg == 1) ? w_ih1 : w_hh1);
    wsh[idx] = (half_t)(src[row * 128 + k] * sc);
  } else if (idx < 204800) {
    int r   = idx - 196608;
    int n   = r >> 4, k = r & 15;
    int g   = (n >> 4) & 3;
    int row = g * 128 + ((n >> 6) << 4) + (n & 15);
    float sc = (g == 2) ? (2.0f * L2E) : (-L2E);
    float v;
    if (k < NIN) v = w_ih0[row * NIN + k] * sc;
    else         v = (b_ih0[row] + b_hh0[row]) * sc;   // bias rides x[15]==1.0
    wsh[idx] = (half_t)v;
  } else if (idx < 205824) {
    int r     = idx - 204800;
    float* bv = (float*)(wsh + 204800);
    int which = r >> 9, n = r & 511;
    int g     = (n >> 4) & 3;
    int row   = g * 128 + ((n >> 6) << 4) + (n & 15);
    float sc  = (g == 2) ? (2.0f * L2E) : (-L2E);
    bv[r] = ((which == 0) ? (b_ih0[row] + b_hh0[row]) : (b_ih1[row] + b_hh1[row])) * sc;
  }
}

__global__ __launch_bounds__(512, 2)
void lstm_kernel(const float* __restrict__ x,
                 const half_t* __restrict__ wsh,
                 const float* __restrict__ fcw,
                 const float* __restrict__ fcb,
                 float* __restrict__ out)
{
  __shared__ __align__(16) half_t sx[SEQ * MB * SXX];   // 51,200 B
  __shared__ __align__(16) half_t sh0[2][MB * SH];      // 8,704 B
  __shared__ __align__(16) half_t sh1[MB * SH];         // 4,352 B (single buffer)
  __shared__ __align__(16) half_t swx[512 * SXS];       // 20,480 B
  __shared__ __align__(16) half_t swi1h[512 * SW3];     // 40,960 B: WI1 k=96..127
  __shared__ __align__(16) half_t sdec[MB * SXX];       // 512 B
  __shared__ __align__(16) float  sbias[512];           // layer-1 bias
  __shared__ __align__(16) float  sfc[258];
  __shared__ __align__(16) float  sc0[512 * 4];         // 8,192 B cell state L0
  __shared__ __align__(16) float  sc1[512 * 4];         // 8,192 B cell state L1
  // total ~145.7 KB

  const half_t* WH0 = wsh;
  const half_t* WI1 = wsh + 65536;
  const half_t* WH1 = wsh + 131072;
  const half_t* WX  = wsh + 196608;
  const float*  BV  = (const float*)(wsh + 204800);

  const int tid   = threadIdx.x;
  const int wave  = tid >> 6;
  const int lane  = tid & 63;
  const int l16   = lane & 15;
  const int quad  = lane >> 4;
  const int nb    = wave * 64;
  const int bbase = blockIdx.x * MB;
  const int wcol  = wave * 16 + l16;   // h-store column for this lane

  // ---- persistent B-fragments: wh0 full (64), wh1 full (64), wi1 kt=0..2 (48) ----
  half8 wh0[4][4], wh1[4][4], wi1[3][4];
  #pragma unroll
  for (int kt = 0; kt < 4; ++kt) {
    #pragma unroll
    for (int g = 0; g < 4; ++g) {
      int n = nb + g * 16 + l16;
      int k = kt * 32 + quad * 8;
      wh0[kt][g] = *(const half8*)&WH0[n * 128 + k];
      wh1[kt][g] = *(const half8*)&WH1[n * 128 + k];
      if (kt < 3) wi1[kt][g] = *(const half8*)&WI1[n * 128 + k];
    }
  }

  // ---- one-time LDS staging ----
  for (int it = tid; it < MB * SEQ * NIN; it += 512) {
    int b = it / (SEQ * NIN); int r = it - b * (SEQ * NIN);
    int s = r / NIN;          int i = r - s * NIN;
    sx[(s * MB + b) * SXX + i] = (half_t)x[(size_t)(bbase + b) * (SEQ * NIN) + r];
  }
  for (int it = tid; it < SEQ * MB; it += 512) sx[it * SXX + 15] = (half_t)1.0f;  // bias carrier
  for (int it = tid; it < 8192; it += 512) {
    int n = it >> 4, k = it & 15;
    swx[n * SXS + k] = WX[it];
  }
  for (int it = tid; it < 16384; it += 512) {       // WI1 kt=3 slice -> LDS
    int n = it >> 5, k = it & 31;
    swi1h[n * SW3 + k] = WI1[n * 128 + 96 + k];
  }
  for (int it = tid; it < 512; it += 512) sbias[it] = BV[512 + it];
  if (tid < 256) sfc[tid] = fcw[tid];
  if (tid < 2)   sfc[256 + tid] = fcb[tid];
  if (tid < 256) {
    int b = tid >> 4, i = tid & 15;
    sdec[b * SXX + i] = (i < NIN) ? (half_t)x[(size_t)(bbase + b) * (SEQ * NIN) + 99 * NIN + i]
                                  : (half_t)1.0f;   // bias carrier
  }
  for (int it = tid; it < MB * SH; it += 512) {
    sh0[0][it] = (half_t)0; sh0[1][it] = (half_t)0; sh1[it] = (half_t)0;
  }
  {
    f32x4 z = (f32x4){0.f, 0.f, 0.f, 0.f};
    *(f32x4*)&sc0[tid * 4] = z;
    *(f32x4*)&sc1[tid * 4] = z;
  }
  __syncthreads();

  f32x4 acc0[4], acc1[4];

  // fused activation (R6-verified): 5 exp2 + 2 rcp per element.
  // CV = in/out cell-state f32x4 (register copy of sc* slot).
  #define ACT_STORE(ACC, CV, DST)                                              \
    _Pragma("unroll")                                                          \
    for (int r = 0; r < 4; ++r) {                                              \
      float A  = __builtin_amdgcn_exp2f((ACC)[0][r]);                          \
      float C  = __builtin_amdgcn_exp2f((ACC)[1][r]);                          \
      float B  = __builtin_amdgcn_exp2f((ACC)[2][r]);                          \
      float D  = __builtin_amdgcn_exp2f((ACC)[3][r]);                          \
      float oA = 1.f + A, oB = 1.f + B, oC = 1.f + C, oD = 1.f + D;            \
      float P  = oA * oB;                                                      \
      float t  = (B - 1.f) * oC;                                               \
      float nm = fmaf((CV)[r], P, t);                                          \
      float rc = __builtin_amdgcn_rcpf(P * oC);                                \
      float cn = nm * rc;                                                      \
      (CV)[r] = cn;                                                            \
      float E  = __builtin_amdgcn_exp2f(2.0f * L2E * cn);                      \
      float h  = (E - 1.f) * __builtin_amdgcn_rcpf(oD * (1.f + E));            \
      int   m  = quad * 4 + r;                                                 \
      (DST)[m * SH + wcol] = (half_t)h;                                        \
    }

  int cur = 0;
  for (int s = 0; s <= TOT; ++s) {
    const int nxt = cur ^ 1;

    // ========== Phase A: acc0 h-part (+enc x-part)  ||  act1(s-1) ==========
    f32x4 c1v = *(const f32x4*)&sc1[tid * 4];   // prefetch c1 (hides under MFMAs)
    if (s < TOT) {
      #pragma unroll
      for (int g = 0; g < 4; ++g) acc0[g] = (f32x4){0.f, 0.f, 0.f, 0.f};
      #pragma unroll
      for (int kt = 0; kt < 4; ++kt) {
        int c = kt * 4 + quad;
        half8 ah = *(const half8*)&sh0[cur][l16 * SH + c * 8];
        #pragma unroll
        for (int g = 0; g < 4; ++g) acc0[g] = MFMA32(ah, wh0[kt][g], acc0[g]);
      }
      if (s < SEQ) {  // encoder x-part early (adds to the ||act1 MFMA pool)
        half4 ax = *(const half4*)&sx[s * MB * SXX + l16 * SXX + quad * 4];
        #pragma unroll
        for (int g = 0; g < 4; ++g) {
          half4 bx = *(const half4*)&swx[(nb + g * 16 + l16) * SXS + quad * 4];
          acc0[g] = MFMA16(ax, bx, acc0[g]);
        }
      }
    }
    if (s > 0) {
      ACT_STORE(acc1, c1v, sh1)               // h1(s-1) -> sh1
      *(f32x4*)&sc1[tid * 4] = c1v;
    }

    // ---- decoder FC(t = s-1) ----
    if (s > SEQ) {
      __syncthreads();  // B2d: h1(s-1) visible
      if (tid < 256) {
        int b   = wave * 4 + (lane >> 4);
        int o   = (lane >> 3) & 1;
        int seg = lane & 7;
        float p = 0.f;
        #pragma unroll
        for (int cc = 0; cc < 2; ++cc) {
          int c = seg * 2 + cc;
          half8 hv = *(const half8*)&sh1[b * SH + c * 8];
          f32x4 w0 = *(const f32x4*)&sfc[o * 128 + c * 8];
          f32x4 w1 = *(const f32x4*)&sfc[o * 128 + c * 8 + 4];
          #pragma unroll
          for (int u = 0; u < 4; ++u) p = fmaf((float)hv[u], w0[u], p);
          #pragma unroll
          for (int u = 0; u < 4; ++u) p = fmaf((float)hv[4 + u], w1[u], p);
        }
        p += __shfl_down(p, 4);
        p += __shfl_down(p, 2);
        p += __shfl_down(p, 1);
        if (seg == 0) {
          p += sfc[256 + o];
          out[(size_t)(bbase + b) * (FUT * 2) + (s - 1 - SEQ) * 2 + o] = p;
          sdec[b * SXX + o] = (half_t)p;   // feedback into features 0:2
        }
      }
      __syncthreads();  // B3d: sdec visible (also serves as the A->B barrier)
    }
    if (s == TOT) break;   // epilogue: final act1+FC done above

    if (s >= SEQ) {  // decoder x-part late (after sdec feedback)
      half4 ax = *(const half4*)&sdec[l16 * SXX + quad * 4];
      #pragma unroll
      for (int g = 0; g < 4; ++g) {
        half4 bx = *(const half4*)&swx[(nb + g * 16 + l16) * SXS + quad * 4];
        acc0[g] = MFMA16(ax, bx, acc0[g]);
      }
    }
    if (s <= SEQ) __syncthreads();  // B2: h1(s-1) stores -> WH1 reads (enc path)

    // ========== Phase B: acc1 = b1 + WH1*h1(s-1)  ||  act0(s) ==========
    f32x4 c0v = *(const f32x4*)&sc0[tid * 4];   // prefetch c0
    #pragma unroll
    for (int g = 0; g < 4; ++g) {
      float b = sbias[nb + g * 16 + l16];
      acc1[g] = (f32x4){b, b, b, b};
    }
    #pragma unroll
    for (int kt = 0; kt < 4; ++kt) {
      int c = kt * 4 + quad;
      half8 ah = *(const half8*)&sh1[l16 * SH + c * 8];
      #pragma unroll
      for (int g = 0; g < 4; ++g) acc1[g] = MFMA32(ah, wh1[kt][g], acc1[g]);
    }
    ACT_STORE(acc0, c0v, (&sh0[nxt][0]))   // h0(s) -> sh0[nxt]
    *(f32x4*)&sc0[tid * 4] = c0v;
    __syncthreads();  // B1: h0(s) visible

    // ========== Phase C: acc1 += WI1*h0(s) ==========
    {
      // kt=3 fragments from LDS; laundered index blocks LICM re-hoisting
      half8 w3[4];
      #pragma unroll
      for (int g = 0; g < 4; ++g) {
        int off = (nb + g * 16 + l16) * SW3 + quad * 8;
        asm volatile("" : "+v"(off));      // opaque: keep load inside the loop
        w3[g] = *(const half8*)&swi1h[off];
      }
      #pragma unroll
      for (int kt = 0; kt < 3; ++kt) {
        int c = kt * 4 + quad;
        half8 ah = *(const half8*)&sh0[nxt][l16 * SH + c * 8];
        #pragma unroll
        for (int g = 0; g < 4; ++g) acc1[g] = MFMA32(ah, wi1[kt][g], acc1[g]);
      }
      {
        int c = 12 + quad;
        half8 ah = *(const half8*)&sh0[nxt][l16 * SH + c * 8];
        #pragma unroll
        for (int g = 0; g < 4; ++g) acc1[g] = MFMA32(ah, w3[g], acc1[g]);
      }
    }

    cur = nxt;
  }
}

extern "C" void kernel_launch(void* const* d_in, const int* in_sizes, int n_in,
                              void* d_out, int out_size, void* d_ws, size_t ws_size,
                              hipStream_t stream)
{
  (void)in_sizes; (void)n_in; (void)out_size; (void)ws_size;
  const float* x     = (const float*)d_in[0];
  const float* w_ih0 = (const float*)d_in[1];
  const float* w_hh0 = (const float*)d_in[2];
  const float* b_ih0 = (const float*)d_in[3];
  const float* b_hh0 = (const float*)d_in[4];
  const float* w_ih1 = (const float*)d_in[5];
  const float* w_hh1 = (const float*)d_in[6];
  const float* b_ih1 = (const float*)d_in[7];
  const float* b_hh1 = (const float*)d_in[8];
  const float* fcw   = (const float*)d_in[9];
  const float* fcb   = (const float*)d_in[10];
  float*  out = (float*)d_out;
  half_t* wsh = (half_t*)d_ws;

  prep_kernel<<<(205824 + 255) / 256, 256, 0, stream>>>(
      w_ih0, w_hh0, b_ih0, b_hh0, w_ih1, w_hh1, b_ih1, b_hh1, wsh);
  lstm_kernel<<<8192 / MB, 512, 0, stream>>>(x, wsh, fcw, fcb, out);
}